// Round 10
// baseline (7291.483 us; speedup 1.0000x reference)
//
#include <hip/hip_runtime.h>

#define MTOT 32768   // B*N
#define KDIM 512     // D
#define CDIM 2048    // C
#define NHALF 1024   // codes per block-half
#define CAPH 16      // candidate slots per row per half
#define TAU  0.032f  // candidate window (~14 sigma of bf16 rounding noise)
#define BM   128     // rows per block
#define NS   64      // K-steps: 4 n-tiles x 16 steps of K=32

// ---- workspace layout (bytes) ----
#define XH_OFF   0u
#define XH_SZ    (MTOT * KDIM * 2u)          // 32 MB bf16 x
#define EH_OFF   (XH_OFF + XH_SZ)
#define EH_SZ    (CDIM * KDIM * 2u)          // 2 MB bf16 normalized codebook
#define INV_OFF  (EH_OFF + EH_SZ)
#define INV_SZ   (CDIM * 4u)
#define CNT_OFF  (INV_OFF + INV_SZ)
#define CNT_SZ   (2u * MTOT * 4u)
#define BV_OFF   (CNT_OFF + CNT_SZ)
#define BV_SZ    (2u * MTOT * 4u)
#define CAND_OFF (BV_OFF + BV_SZ)
#define CAND_SZ  (MTOT * 32u * 2u)           // u16 codes, [row][2*CAPH]
#define WS_NEEDED (CAND_OFF + CAND_SZ)

typedef short  short8 __attribute__((ext_vector_type(8)));
typedef float  f32x4  __attribute__((ext_vector_type(4)));

__device__ inline unsigned short f2bf(float f) {
    unsigned u = __float_as_uint(f);
    return (unsigned short)((u + 0x7FFFu + ((u >> 16) & 1u)) >> 16);  // RTNE
}
__device__ inline unsigned fkey(float f) {          // order-preserving f32->u32
    unsigned u = __float_as_uint(f);
    return (u & 0x80000000u) ? ~u : (u | 0x80000000u);
}
__device__ inline float fkey_inv(unsigned k) {
    unsigned u = (k & 0x80000000u) ? (k ^ 0x80000000u) : ~k;
    return __uint_as_float(u);
}
__device__ __forceinline__ void async16(void* lds, const void* g) {
    __builtin_amdgcn_global_load_lds(
        (const __attribute__((address_space(1))) unsigned int*)g,
        (__attribute__((address_space(3))) unsigned int*)lds, 16, 0, 0);
}

// ---------------- codebook norms + bf16 normalized codebook ----------------
__global__ __launch_bounds__(256, 1)
void vq_norm_eh_kernel(const float* __restrict__ embed, float* __restrict__ inv_norm,
                       unsigned short* __restrict__ eh) {
    const int row  = blockIdx.x * 4 + (threadIdx.x >> 6);
    const int lane = threadIdx.x & 63;
    const float4 v0 = *(const float4*)&embed[(size_t)row * KDIM + lane * 8];
    const float4 v1 = *(const float4*)&embed[(size_t)row * KDIM + lane * 8 + 4];
    float ss = v0.x*v0.x + v0.y*v0.y + v0.z*v0.z + v0.w*v0.w
             + v1.x*v1.x + v1.y*v1.y + v1.z*v1.z + v1.w*v1.w;
#pragma unroll
    for (int off = 32; off >= 1; off >>= 1) ss += __shfl_xor(ss, off, 64);
    float inv = 1.0f / fmaxf(sqrtf(ss), 1e-12f);
    if (lane == 0) inv_norm[row] = inv;
    short8 o;
    o[0] = (short)f2bf(v0.x * inv); o[1] = (short)f2bf(v0.y * inv);
    o[2] = (short)f2bf(v0.z * inv); o[3] = (short)f2bf(v0.w * inv);
    o[4] = (short)f2bf(v1.x * inv); o[5] = (short)f2bf(v1.y * inv);
    o[6] = (short)f2bf(v1.z * inv); o[7] = (short)f2bf(v1.w * inv);
    *(short8*)&eh[(size_t)row * KDIM + lane * 8] = o;
}

// ---------------- x -> bf16 ----------------
__global__ __launch_bounds__(256, 1)
void vq_convx_kernel(const float* __restrict__ x, unsigned short* __restrict__ xh) {
    const size_t base = ((size_t)blockIdx.x * 256 + threadIdx.x) * 8;
    const float4 a = *(const float4*)&x[base];
    const float4 b = *(const float4*)&x[base + 4];
    short8 o;
    o[0] = (short)f2bf(a.x); o[1] = (short)f2bf(a.y);
    o[2] = (short)f2bf(a.z); o[3] = (short)f2bf(a.w);
    o[4] = (short)f2bf(b.x); o[5] = (short)f2bf(b.y);
    o[6] = (short)f2bf(b.z); o[7] = (short)f2bf(b.w);
    *(short8*)&xh[base] = o;
}

// ---------------- phase 1: bf16 MFMA GEMM + max + candidate window ----------------
// Grid = (MTOT/128)*2 halves = 512 blocks -> 2 blocks/CU (53 KB LDS each).
// 8 waves 2(m)x4(n); wave tile 64x64 = 4x4 fragments of 16x16; BK=32.
// A: per-lane register prefetch direct from global (ping-pong af[2][4], 1 step ahead).
// B: triple-buffered swizzled LDS via global_load_lds, 2-step prefetch.
// In-order vmcnt retire: at each wait, outstanding = [B(s):2, A(s):4, B(s+1):2];
// vmcnt(6) retires exactly B(s); A(s) is covered by compiler's dependence waitcnt.
__global__ __launch_bounds__(512, 4)
void vq_phase1_kernel(const unsigned short* __restrict__ xh,
                      const unsigned short* __restrict__ eh,
                      unsigned* __restrict__ cnt_g, float* __restrict__ bv_g,
                      unsigned short* __restrict__ cand_g) {
    __shared__ __align__(16) char bbuf[3 * 16384];   // 48 KB: 3 x (256 codes x 32k x 2B)
    __shared__ unsigned runmax[BM];
    __shared__ unsigned cnt[BM];
    __shared__ unsigned short cand[BM][CAPH];

    const int tid  = threadIdx.x;
    const int lane = tid & 63;
    const int wid  = tid >> 6;
    const int wr   = wid >> 2;          // 0..1 -> 64 rows
    const int wc   = wid & 3;           // 0..3 -> 64 codes
    const int bid  = blockIdx.x;
    const int m0   = (bid >> 1) * BM;
    const int half = bid & 1;
    const int n0b  = half * NHALF;

    const int laneRow = lane & 15;
    const int laneK8  = lane >> 4;              // 0..3 -> k-chunk of 8
    const int rr      = laneRow >> 1;           // 0..7
    const int slot8s  = (((laneRow & 1) << 2) + laneK8) ^ rr;

    if (tid < BM) { runmax[tid] = 0u; cnt[tid] = 0u; }

    // B ds_read base (all variation is compile-time immediate)
    const char* bRd = bbuf + (wc * 4096 + rr * 128 + slot8s * 16);

    // B staging source pointers (layout-inverse swizzle, rule 21)
    const unsigned short* bSrc[2];
#pragma unroll
    for (int l = 0; l < 2; ++l) {
        int slot = l * 512 + tid;
        int rp   = slot >> 3;                   // 0..127
        int s8   = (slot & 7) ^ (rp & 7);
        int row  = rp * 2 + (s8 >> 2);          // 0..255
        int k8   = s8 & 3;
        bSrc[l] = eh + (size_t)(n0b + row) * KDIM + k8 * 8;
    }
    const int ldsW  = wid * 1024;               // wave-uniform dest base
    const int ldsW1 = 8192 + wid * 1024;

    // A per-lane fragment pointers: 16B at (row = m0+wr*64+ai*16+laneRow, k-chunk laneK8*8)
    const unsigned short* aP[4];
#pragma unroll
    for (int ai = 0; ai < 4; ++ai)
        aP[ai] = xh + (size_t)(m0 + wr * 64 + ai * 16 + laneRow) * KDIM + laneK8 * 8;

    f32x4  acc[4][4];
    short8 af[2][4];

#define STAGEB(S) {                                                       \
        const int _bo = ((S) >> 4) * 131072 + ((S) & 15) * 32;            \
        async16(bbuf + ((S) % 3) * 16384 + ldsW,  bSrc[0] + _bo);         \
        async16(bbuf + ((S) % 3) * 16384 + ldsW1, bSrc[1] + _bo);         \
    }

    STAGEB(0);
    __builtin_amdgcn_sched_barrier(0);          // pin B(0) at vm-queue head
#pragma unroll
    for (int ai = 0; ai < 4; ++ai) af[0][ai] = *(const short8*)aP[ai];
    STAGEB(1);

#pragma unroll
    for (int s = 0; s < NS; ++s) {
        if (s == NS - 1) { asm volatile("s_waitcnt vmcnt(0)" ::: "memory"); }
        else             { asm volatile("s_waitcnt vmcnt(6)" ::: "memory"); }
        __builtin_amdgcn_sched_barrier(0);
        __builtin_amdgcn_s_barrier();
        __builtin_amdgcn_sched_barrier(0);

        if (s + 1 < NS) {                       // A(s+1) -> ping-pong regs
            const int ko = ((s + 1) & 15) * 32;
#pragma unroll
            for (int ai = 0; ai < 4; ++ai)
                af[(s + 1) & 1][ai] = *(const short8*)(aP[ai] + ko);
        }
        if (s + 2 < NS) STAGEB(s + 2);          // B(s+2) -> LDS buf (s+2)%3

        if ((s & 15) == 0) {
#pragma unroll
            for (int i = 0; i < 4; ++i)
#pragma unroll
                for (int j = 0; j < 4; ++j) acc[i][j] = (f32x4)0.0f;
        }

        short8 bf[4];
#pragma unroll
        for (int aj = 0; aj < 4; ++aj)
            bf[aj] = *(const short8*)(bRd + (s % 3) * 16384 + aj * 1024);

        __builtin_amdgcn_s_setprio(1);
#pragma unroll
        for (int ai = 0; ai < 4; ++ai)
#pragma unroll
            for (int aj = 0; aj < 4; ++aj)
                acc[ai][aj] = __builtin_amdgcn_mfma_f32_16x16x32_bf16(
                    af[s & 1][ai], bf[aj], acc[ai][aj], 0, 0, 0);
        __builtin_amdgcn_s_setprio(0);

        if ((s & 15) == 15) {                   // end of one 256-code n-tile
            const int _n0 = n0b + (s >> 4) * 256;
#pragma unroll
            for (int ai = 0; ai < 4; ++ai) {
#pragma unroll
                for (int r = 0; r < 4; ++r) {
                    float v = fmaxf(fmaxf(acc[ai][0][r], acc[ai][1][r]),
                                    fmaxf(acc[ai][2][r], acc[ai][3][r]));
#pragma unroll
                    for (int off = 8; off >= 1; off >>= 1)
                        v = fmaxf(v, __shfl_xor(v, off, 64));
                    if (laneRow == 0)
                        atomicMax(&runmax[wr * 64 + ai * 16 + laneK8 * 4 + r], fkey(v));
                }
            }
            asm volatile("s_waitcnt lgkmcnt(0)" ::: "memory");
            __builtin_amdgcn_sched_barrier(0);
            __builtin_amdgcn_s_barrier();
            __builtin_amdgcn_sched_barrier(0);
#pragma unroll
            for (int ai = 0; ai < 4; ++ai) {
                const int _rb = wr * 64 + ai * 16 + laneK8 * 4;
#pragma unroll
                for (int r = 0; r < 4; ++r) {
                    float th = fkey_inv(runmax[_rb + r]) - TAU;
#pragma unroll
                    for (int aj = 0; aj < 4; ++aj) {
                        if (acc[ai][aj][r] >= th) {
                            unsigned idx = atomicAdd(&cnt[_rb + r], 1u);
                            if (idx < CAPH)
                                cand[_rb + r][idx] = (unsigned short)
                                    (_n0 + wc * 64 + aj * 16 + laneRow);
                        }
                    }
                }
            }
        }
    }
#undef STAGEB

    __syncthreads();
    if (tid < BM) {
        cnt_g[(size_t)half * MTOT + m0 + tid] = cnt[tid];              // RAW count
        bv_g [(size_t)half * MTOT + m0 + tid] = fkey_inv(runmax[tid]);
    }
#pragma unroll
    for (int l = 0; l < 4; ++l) {
        int i = tid + l * 512;           // 0..2047 = 128 rows x 16 slots
        int row = i >> 4, sl = i & 15;
        cand_g[(size_t)(m0 + row) * 32 + half * 16 + sl] = cand[row][sl];
    }
}

// ---------------- phase 2: cross-half resolve + rare fp32 rescore + gather ----------
__global__ __launch_bounds__(256, 2)
void vq_phase2_kernel(const float* __restrict__ x, const float* __restrict__ embed,
                      const float* __restrict__ inv_norm,
                      const unsigned* __restrict__ cnt_g, const float* __restrict__ bv_g,
                      const unsigned short* __restrict__ cand_g,
                      float* __restrict__ out_q, float* __restrict__ out_i) {
    const int r    = blockIdx.x * 4 + (threadIdx.x >> 6);
    const int lane = threadIdx.x & 63;

    const unsigned c0 = cnt_g[r], c1 = cnt_g[(size_t)MTOT + r];
    const float bv0 = bv_g[r], bv1 = bv_g[(size_t)MTOT + r];
    const int   lead = (bv1 > bv0) ? 1 : 0;
    const float gap  = fabsf(bv0 - bv1);
    const unsigned cl = lead ? c1 : c0;

    int bestc;
    if (gap > TAU && cl == 1) {
        bestc = (int)cand_g[(size_t)r * 32 + lead * 16];   // unique near-max candidate
    } else {
        const float4 xa = *(const float4*)&x[(size_t)r * KDIM + lane * 8];
        const float4 xb = *(const float4*)&x[(size_t)r * KDIM + lane * 8 + 4];
        float bestv = -3.4e38f; bestc = 1 << 30;

        auto score = [&](int c) {
            float inv = inv_norm[c];
            const float4 ea = *(const float4*)&embed[(size_t)c * KDIM + lane * 8];
            const float4 eb = *(const float4*)&embed[(size_t)c * KDIM + lane * 8 + 4];
            float s = 0.f;
            s = fmaf(xa.x, ea.x * inv, s); s = fmaf(xa.y, ea.y * inv, s);
            s = fmaf(xa.z, ea.z * inv, s); s = fmaf(xa.w, ea.w * inv, s);
            s = fmaf(xb.x, eb.x * inv, s); s = fmaf(xb.y, eb.y * inv, s);
            s = fmaf(xb.z, eb.z * inv, s); s = fmaf(xb.w, eb.w * inv, s);
#pragma unroll
            for (int off = 32; off >= 1; off >>= 1) s += __shfl_xor(s, off, 64);
            if (s > bestv || (s == bestv && c < bestc)) { bestv = s; bestc = c; }
        };

        const int h0 = (gap > TAU) ? lead : 0;
        const int h1 = (gap > TAU) ? lead : 1;
        for (int h = h0; h <= h1; ++h) {
            const unsigned ch = h ? c1 : c0;
            if (ch <= CAPH) {
                for (unsigned i = 0; i < ch; ++i)
                    score((int)cand_g[(size_t)r * 32 + h * 16 + i]);
            } else {
                // candidate list overflowed (P ~ 1e-9/half-row): exact scan of the half
                for (int c = h * NHALF; c < h * NHALF + NHALF; ++c) score(c);
            }
        }
    }

    if (lane == 0) out_i[r] = (float)bestc;
    const float4 qa = *(const float4*)&embed[(size_t)bestc * KDIM + lane * 8];
    const float4 qb = *(const float4*)&embed[(size_t)bestc * KDIM + lane * 8 + 4];
    *(float4*)&out_q[(size_t)r * KDIM + lane * 8]     = qa;
    *(float4*)&out_q[(size_t)r * KDIM + lane * 8 + 4] = qb;
}

// ================= fallback (round-2 kernel, known correct) =================
#define FBM   64
#define FBN   256
#define FBK   16

__global__ __launch_bounds__(256, 1)
void vq_norm_kernel(const float* __restrict__ embed, float* __restrict__ inv_norm) {
    const int row  = blockIdx.x * 4 + (threadIdx.x >> 6);
    const int lane = threadIdx.x & 63;
    const float* e = embed + (size_t)row * KDIM;
    float ss = 0.f;
#pragma unroll
    for (int p = 0; p < 8; ++p) { float v = e[lane + 64 * p]; ss = fmaf(v, v, ss); }
#pragma unroll
    for (int off = 32; off >= 1; off >>= 1) ss += __shfl_xor(ss, off, 64);
    if (lane == 0) inv_norm[row] = 1.0f / fmaxf(sqrtf(ss), 1e-12f);
}

__global__ __launch_bounds__(256, 2)
void vq_main_kernel(const float* __restrict__ x, const float* __restrict__ embed,
                    const float* __restrict__ inv_norm,
                    float* __restrict__ out_q, float* __restrict__ out_i) {
    __shared__ float As[FBK][FBM + 4];
    __shared__ float Bs[FBK][FBN + 4];
    __shared__ float best_val[FBM];
    __shared__ int   best_idx[FBM];
    const int tid = threadIdx.x;
    const int m0  = blockIdx.x * FBM;
    const int ty  = tid >> 5, tx = tid & 31;
    if (tid < FBM) { best_val[tid] = -3.0e38f; best_idx[tid] = 0; }
    const int am = tid >> 2, k4 = (tid & 3) << 2, bc = tid >> 2;
    float acc[8][8];
    for (int n0 = 0; n0 < CDIM; n0 += FBN) {
        float bs0 = inv_norm[n0+bc], bs1 = inv_norm[n0+bc+64], bs2 = inv_norm[n0+bc+128], bs3 = inv_norm[n0+bc+192];
#pragma unroll
        for (int i = 0; i < 8; ++i)
#pragma unroll
            for (int j = 0; j < 8; ++j) acc[i][j] = 0.f;
        float4 aReg = *(const float4*)&x[(size_t)(m0+am)*KDIM + k4];
        float4 b0 = *(const float4*)&embed[(size_t)(n0+bc)*KDIM + k4];
        float4 b1 = *(const float4*)&embed[(size_t)(n0+bc+64)*KDIM + k4];
        float4 b2 = *(const float4*)&embed[(size_t)(n0+bc+128)*KDIM + k4];
        float4 b3 = *(const float4*)&embed[(size_t)(n0+bc+192)*KDIM + k4];
        for (int kt = 0; kt < KDIM; kt += FBK) {
            __syncthreads();
            As[k4+0][am]=aReg.x; As[k4+1][am]=aReg.y; As[k4+2][am]=aReg.z; As[k4+3][am]=aReg.w;
            Bs[k4+0][bc]=b0.x*bs0; Bs[k4+1][bc]=b0.y*bs0; Bs[k4+2][bc]=b0.z*bs0; Bs[k4+3][bc]=b0.w*bs0;
            Bs[k4+0][bc+64]=b1.x*bs1; Bs[k4+1][bc+64]=b1.y*bs1; Bs[k4+2][bc+64]=b1.z*bs1; Bs[k4+3][bc+64]=b1.w*bs1;
            Bs[k4+0][bc+128]=b2.x*bs2; Bs[k4+1][bc+128]=b2.y*bs2; Bs[k4+2][bc+128]=b2.z*bs2; Bs[k4+3][bc+128]=b2.w*bs2;
            Bs[k4+0][bc+192]=b3.x*bs3; Bs[k4+1][bc+192]=b3.y*bs3; Bs[k4+2][bc+192]=b3.z*bs3; Bs[k4+3][bc+192]=b3.w*bs3;
            __syncthreads();
            if (kt + FBK < KDIM) {
                int kn = kt + FBK + k4;
                aReg = *(const float4*)&x[(size_t)(m0+am)*KDIM + kn];
                b0 = *(const float4*)&embed[(size_t)(n0+bc)*KDIM + kn];
                b1 = *(const float4*)&embed[(size_t)(n0+bc+64)*KDIM + kn];
                b2 = *(const float4*)&embed[(size_t)(n0+bc+128)*KDIM + kn];
                b3 = *(const float4*)&embed[(size_t)(n0+bc+192)*KDIM + kn];
            }
#pragma unroll 4
            for (int k = 0; k < FBK; ++k) {
                float a[8], b[8];
                *(float4*)&a[0] = *(const float4*)&As[k][ty*8];
                *(float4*)&a[4] = *(const float4*)&As[k][ty*8+4];
                *(float4*)&b[0] = *(const float4*)&Bs[k][tx*4];
                *(float4*)&b[4] = *(const float4*)&Bs[k][128+tx*4];
#pragma unroll
                for (int i = 0; i < 8; ++i)
#pragma unroll
                    for (int j = 0; j < 8; ++j) acc[i][j] = fmaf(a[i], b[j], acc[i][j]);
            }
        }
#pragma unroll
        for (int i = 0; i < 8; ++i) {
            float v = acc[i][0]; int jj = 0;
#pragma unroll
            for (int j = 1; j < 8; ++j) if (acc[i][j] > v) { v = acc[i][j]; jj = j; }
            int col = n0 + ((jj < 4) ? (tx*4+jj) : (128 + tx*4 + (jj-4)));
#pragma unroll
            for (int off = 16; off >= 1; off >>= 1) {
                float ov = __shfl_xor(v, off, 64);
                int   oc = __shfl_xor(col, off, 64);
                if (ov > v || (ov == v && oc < col)) { v = ov; col = oc; }
            }
            if (tx == 0) {
                int r = ty*8+i;
                if (v > best_val[r] || (v == best_val[r] && col < best_idx[r])) { best_val[r]=v; best_idx[r]=col; }
            }
        }
    }
    __syncthreads();
    if (tid < FBM) out_i[m0 + tid] = (float)best_idx[tid];
#pragma unroll 1
    for (int rp = 0; rp < FBM; rp += 2) {
        int r = rp + (tid >> 7), slot = tid & 127, src = best_idx[r];
        const float4 v = *(const float4*)&embed[(size_t)src*KDIM + slot*4];
        *(float4*)&out_q[(size_t)(m0+r)*KDIM + slot*4] = v;
    }
}

extern "C" void kernel_launch(void* const* d_in, const int* in_sizes, int n_in,
                              void* d_out, int out_size, void* d_ws, size_t ws_size,
                              hipStream_t stream) {
    const float* x     = (const float*)d_in[0];
    const float* embed = (const float*)d_in[1];
    float* out_q = (float*)d_out;
    float* out_i = (float*)d_out + (size_t)MTOT * KDIM;
    char*  ws    = (char*)d_ws;

    if (ws_size >= (size_t)WS_NEEDED) {
        unsigned short* xh  = (unsigned short*)(ws + XH_OFF);
        unsigned short* eh  = (unsigned short*)(ws + EH_OFF);
        float*          inv = (float*)(ws + INV_OFF);
        unsigned*       cnt = (unsigned*)(ws + CNT_OFF);
        float*          bv  = (float*)(ws + BV_OFF);
        unsigned short* cnd = (unsigned short*)(ws + CAND_OFF);

        vq_norm_eh_kernel<<<CDIM / 4, 256, 0, stream>>>(embed, inv, eh);
        vq_convx_kernel<<<(MTOT * KDIM / 8) / 256, 256, 0, stream>>>(x, xh);
        vq_phase1_kernel<<<(MTOT / BM) * 2, 512, 0, stream>>>(xh, eh, cnt, bv, cnd);
        vq_phase2_kernel<<<MTOT / 4, 256, 0, stream>>>(x, embed, inv, cnt, bv, cnd, out_q, out_i);
    } else {
        float* inv = (float*)ws;   // 8 KB
        vq_norm_kernel<<<CDIM / 4, 256, 0, stream>>>(embed, inv);
        vq_main_kernel<<<MTOT / FBM, 256, 0, stream>>>(x, embed, inv, out_q, out_i);
    }
}

// Round 11
// 213.341 us; speedup vs baseline: 34.1775x; 34.1775x over previous
//
#include <hip/hip_runtime.h>

#define MTOT 32768   // B*N
#define KDIM 512     // D
#define CDIM 2048    // C
#define NHALF 1024   // codes per block-half
#define CAPH 16      // candidate slots per row per half
#define TAU  0.032f  // candidate window (~14 sigma of bf16 rounding noise)
#define BM   128     // rows per block

// ---- workspace layout (bytes) ----
#define XH_OFF   0u
#define XH_SZ    (MTOT * KDIM * 2u)          // 32 MB bf16 x
#define EH_OFF   (XH_OFF + XH_SZ)
#define EH_SZ    (CDIM * KDIM * 2u)          // 2 MB bf16 normalized codebook
#define INV_OFF  (EH_OFF + EH_SZ)
#define INV_SZ   (CDIM * 4u)
#define CNT_OFF  (INV_OFF + INV_SZ)
#define CNT_SZ   (2u * MTOT * 4u)
#define BV_OFF   (CNT_OFF + CNT_SZ)
#define BV_SZ    (2u * MTOT * 4u)
#define CAND_OFF (BV_OFF + BV_SZ)
#define CAND_SZ  (MTOT * 32u * 2u)           // u16 codes, [row][2*CAPH]
#define WS_NEEDED (CAND_OFF + CAND_SZ)

typedef short  short8 __attribute__((ext_vector_type(8)));
typedef float  f32x4  __attribute__((ext_vector_type(4)));

__device__ inline unsigned short f2bf(float f) {
    unsigned u = __float_as_uint(f);
    return (unsigned short)((u + 0x7FFFu + ((u >> 16) & 1u)) >> 16);  // RTNE
}
__device__ inline unsigned fkey(float f) {          // order-preserving f32->u32
    unsigned u = __float_as_uint(f);
    return (u & 0x80000000u) ? ~u : (u | 0x80000000u);
}
__device__ inline float fkey_inv(unsigned k) {
    unsigned u = (k & 0x80000000u) ? (k ^ 0x80000000u) : ~k;
    return __uint_as_float(u);
}
__device__ __forceinline__ void async16(void* lds, const void* g) {
    __builtin_amdgcn_global_load_lds(
        (const __attribute__((address_space(1))) unsigned int*)g,
        (__attribute__((address_space(3))) unsigned int*)lds, 16, 0, 0);
}

// ---------------- codebook norms + bf16 normalized codebook ----------------
__global__ __launch_bounds__(256, 1)
void vq_norm_eh_kernel(const float* __restrict__ embed, float* __restrict__ inv_norm,
                       unsigned short* __restrict__ eh) {
    const int row  = blockIdx.x * 4 + (threadIdx.x >> 6);
    const int lane = threadIdx.x & 63;
    const float4 v0 = *(const float4*)&embed[(size_t)row * KDIM + lane * 8];
    const float4 v1 = *(const float4*)&embed[(size_t)row * KDIM + lane * 8 + 4];
    float ss = v0.x*v0.x + v0.y*v0.y + v0.z*v0.z + v0.w*v0.w
             + v1.x*v1.x + v1.y*v1.y + v1.z*v1.z + v1.w*v1.w;
#pragma unroll
    for (int off = 32; off >= 1; off >>= 1) ss += __shfl_xor(ss, off, 64);
    float inv = 1.0f / fmaxf(sqrtf(ss), 1e-12f);
    if (lane == 0) inv_norm[row] = inv;
    short8 o;
    o[0] = (short)f2bf(v0.x * inv); o[1] = (short)f2bf(v0.y * inv);
    o[2] = (short)f2bf(v0.z * inv); o[3] = (short)f2bf(v0.w * inv);
    o[4] = (short)f2bf(v1.x * inv); o[5] = (short)f2bf(v1.y * inv);
    o[6] = (short)f2bf(v1.z * inv); o[7] = (short)f2bf(v1.w * inv);
    *(short8*)&eh[(size_t)row * KDIM + lane * 8] = o;
}

// ---------------- x -> bf16 ----------------
__global__ __launch_bounds__(256, 1)
void vq_convx_kernel(const float* __restrict__ x, unsigned short* __restrict__ xh) {
    const size_t base = ((size_t)blockIdx.x * 256 + threadIdx.x) * 8;
    const float4 a = *(const float4*)&x[base];
    const float4 b = *(const float4*)&x[base + 4];
    short8 o;
    o[0] = (short)f2bf(a.x); o[1] = (short)f2bf(a.y);
    o[2] = (short)f2bf(a.z); o[3] = (short)f2bf(a.w);
    o[4] = (short)f2bf(b.x); o[5] = (short)f2bf(b.y);
    o[6] = (short)f2bf(b.z); o[7] = (short)f2bf(b.w);
    *(short8*)&xh[base] = o;
}

// ---------------- phase 1: bf16 MFMA GEMM + max + candidate window ----------------
// Grid = (MTOT/128)*2 halves = 512 blocks -> 2 blocks/CU (~70 KB LDS each).
// 8 waves 2(m)x4(n); wave tile 64x64 = 4x4 fragments of 16x16; BK=32.
// A: per-lane 16B fragment loads DIRECT from global each step (xh is L3-resident,
//    panel L2-warm after first n-tile). No A LDS traffic at all.
// B: 4-deep swizzled LDS via global_load_lds (buf = k&3, all offsets immediate).
// vmcnt ledger (in-order retire): step issues [af:4, B(s+2):2]; compiler's af-wait
// = vmcnt(2) retires B(s+1); explicit start-of-step vmcnt(2) guarantees B(s).
// Register ledger: 64 acc(AGPR) + ~46 VGPR < 128 @ 4 waves/SIMD -> no spill.
__global__ __launch_bounds__(512, 4)
void vq_phase1_kernel(const unsigned short* __restrict__ xh,
                      const unsigned short* __restrict__ eh,
                      unsigned* __restrict__ cnt_g, float* __restrict__ bv_g,
                      unsigned short* __restrict__ cand_g) {
    __shared__ __align__(16) char bbuf[4 * 16384];   // 64 KB: 4 x (256 codes x 32k x 2B)
    __shared__ unsigned runmax[BM];
    __shared__ unsigned cnt[BM];
    __shared__ unsigned short cand[BM][CAPH];

    const int tid  = threadIdx.x;
    const int lane = tid & 63;
    const int wid  = tid >> 6;
    const int wr   = wid >> 2;          // 0..1 -> 64 rows
    const int wc   = wid & 3;           // 0..3 -> 64 codes
    const int bid  = blockIdx.x;
    const int m0   = (bid >> 1) * BM;
    const int half = bid & 1;
    const int n0b  = half * NHALF;

    const int laneRow = lane & 15;
    const int laneK8  = lane >> 4;              // 0..3 -> k-chunk of 8
    const int rr      = laneRow >> 1;           // 0..7
    const int slot8s  = (((laneRow & 1) << 2) + laneK8) ^ rr;

    if (tid < BM) { runmax[tid] = 0u; cnt[tid] = 0u; }

    // B ds_read base (all variation is compile-time immediate)
    const char* bRd = bbuf + (wc * 4096 + rr * 128 + slot8s * 16);

    // B staging source pointers (layout-inverse swizzle, rule 21)
    const unsigned short* bSrc0;
    const unsigned short* bSrc1;
    {
        int slot = tid;
        int rp   = slot >> 3;
        int s8   = (slot & 7) ^ (rp & 7);
        bSrc0 = eh + (size_t)(n0b + rp * 2 + (s8 >> 2)) * KDIM + (s8 & 3) * 8;
        slot = 512 + tid;
        rp   = slot >> 3;
        s8   = (slot & 7) ^ (rp & 7);
        bSrc1 = eh + (size_t)(n0b + rp * 2 + (s8 >> 2)) * KDIM + (s8 & 3) * 8;
    }
    const int ldsW  = wid * 1024;               // wave-uniform dest base
    const int ldsW1 = 8192 + wid * 1024;

    // A per-lane fragment pointers (row = m0+wr*64+ai*16+laneRow, k-chunk laneK8*8)
    const unsigned short* aP[4];
#pragma unroll
    for (int ai = 0; ai < 4; ++ai)
        aP[ai] = xh + (size_t)(m0 + wr * 64 + ai * 16 + laneRow) * KDIM + laneK8 * 8;

    f32x4 acc[4][4];

    // prologue: stage B(0), B(1)
    async16(bbuf + 0 * 16384 + ldsW,  bSrc0 + 0);
    async16(bbuf + 0 * 16384 + ldsW1, bSrc1 + 0);
    async16(bbuf + 1 * 16384 + ldsW,  bSrc0 + 32);
    async16(bbuf + 1 * 16384 + ldsW1, bSrc1 + 32);

#pragma unroll 1
    for (int nt = 0; nt < 4; ++nt) {
        const unsigned short* bNxt0 = bSrc0 + 131072;   // next 256-code tile
        const unsigned short* bNxt1 = bSrc1 + 131072;
        const unsigned short* aB    = aP[0] + 0;        // keep aP in regs
        (void)aB;

#pragma unroll
        for (int k = 0; k < 16; ++k) {
            if (nt == 3 && k == 15) { asm volatile("s_waitcnt vmcnt(0)" ::: "memory"); }
            else                    { asm volatile("s_waitcnt vmcnt(2)" ::: "memory"); }
            __builtin_amdgcn_sched_barrier(0);
            __builtin_amdgcn_s_barrier();
            __builtin_amdgcn_sched_barrier(0);

            // A(s) fragments: direct global loads (L2/L3-warm), static k offsets
            short8 af[4];
#pragma unroll
            for (int ai = 0; ai < 4; ++ai)
                af[ai] = *(const short8*)(aP[ai] + k * 32);

            // stage B(s+2) into buf (k+2)&3
            if (!(nt == 3 && k >= 14)) {
                if (k < 14) {
                    async16(bbuf + ((k + 2) & 3) * 16384 + ldsW,  bSrc0 + (k + 2) * 32);
                    async16(bbuf + ((k + 2) & 3) * 16384 + ldsW1, bSrc1 + (k + 2) * 32);
                } else {
                    async16(bbuf + ((k + 2) & 3) * 16384 + ldsW,  bNxt0 + (k - 14) * 32);
                    async16(bbuf + ((k + 2) & 3) * 16384 + ldsW1, bNxt1 + (k - 14) * 32);
                }
            }

            if (k == 0) {
#pragma unroll
                for (int i = 0; i < 4; ++i)
#pragma unroll
                    for (int j = 0; j < 4; ++j) acc[i][j] = (f32x4)0.0f;
            }

            __builtin_amdgcn_s_setprio(1);
#pragma unroll
            for (int aj = 0; aj < 4; ++aj) {           // one live bf fragment
                short8 bf = *(const short8*)(bRd + (k & 3) * 16384 + aj * 1024);
#pragma unroll
                for (int ai = 0; ai < 4; ++ai)
                    acc[ai][aj] = __builtin_amdgcn_mfma_f32_16x16x32_bf16(
                        af[ai], bf, acc[ai][aj], 0, 0, 0);
            }
            __builtin_amdgcn_s_setprio(0);

            if (k == 15) {                             // end of one 256-code n-tile
                const int _n0 = n0b + nt * 256;
#pragma unroll
                for (int ai = 0; ai < 4; ++ai) {
#pragma unroll
                    for (int r = 0; r < 4; ++r) {
                        float v = fmaxf(fmaxf(acc[ai][0][r], acc[ai][1][r]),
                                        fmaxf(acc[ai][2][r], acc[ai][3][r]));
#pragma unroll
                        for (int off = 8; off >= 1; off >>= 1)
                            v = fmaxf(v, __shfl_xor(v, off, 64));
                        if (laneRow == 0)
                            atomicMax(&runmax[wr * 64 + ai * 16 + laneK8 * 4 + r], fkey(v));
                    }
                }
                asm volatile("s_waitcnt lgkmcnt(0)" ::: "memory");
                __builtin_amdgcn_sched_barrier(0);
                __builtin_amdgcn_s_barrier();
                __builtin_amdgcn_sched_barrier(0);
#pragma unroll
                for (int ai = 0; ai < 4; ++ai) {
                    const int _rb = wr * 64 + ai * 16 + laneK8 * 4;
#pragma unroll
                    for (int r = 0; r < 4; ++r) {
                        float th = fkey_inv(runmax[_rb + r]) - TAU;
#pragma unroll
                        for (int aj = 0; aj < 4; ++aj) {
                            if (acc[ai][aj][r] >= th) {
                                unsigned idx = atomicAdd(&cnt[_rb + r], 1u);
                                if (idx < CAPH)
                                    cand[_rb + r][idx] = (unsigned short)
                                        (_n0 + wc * 64 + aj * 16 + laneRow);
                            }
                        }
                    }
                }
            }
        }
        bSrc0 = bNxt0; bSrc1 = bNxt1;
    }

    __syncthreads();
    if (tid < BM) {
        cnt_g[(size_t)half * MTOT + m0 + tid] = cnt[tid];              // RAW count
        bv_g [(size_t)half * MTOT + m0 + tid] = fkey_inv(runmax[tid]);
    }
#pragma unroll
    for (int l = 0; l < 4; ++l) {
        int i = tid + l * 512;           // 0..2047 = 128 rows x 16 slots
        int row = i >> 4, sl = i & 15;
        cand_g[(size_t)(m0 + row) * 32 + half * 16 + sl] = cand[row][sl];
    }
}

// ---------------- phase 2: cross-half resolve + rare fp32 rescore + gather ----------
__global__ __launch_bounds__(256, 2)
void vq_phase2_kernel(const float* __restrict__ x, const float* __restrict__ embed,
                      const float* __restrict__ inv_norm,
                      const unsigned* __restrict__ cnt_g, const float* __restrict__ bv_g,
                      const unsigned short* __restrict__ cand_g,
                      float* __restrict__ out_q, float* __restrict__ out_i) {
    const int r    = blockIdx.x * 4 + (threadIdx.x >> 6);
    const int lane = threadIdx.x & 63;

    const unsigned c0 = cnt_g[r], c1 = cnt_g[(size_t)MTOT + r];
    const float bv0 = bv_g[r], bv1 = bv_g[(size_t)MTOT + r];
    const int   lead = (bv1 > bv0) ? 1 : 0;
    const float gap  = fabsf(bv0 - bv1);
    const unsigned cl = lead ? c1 : c0;

    int bestc;
    if (gap > TAU && cl == 1) {
        bestc = (int)cand_g[(size_t)r * 32 + lead * 16];   // unique near-max candidate
    } else {
        const float4 xa = *(const float4*)&x[(size_t)r * KDIM + lane * 8];
        const float4 xb = *(const float4*)&x[(size_t)r * KDIM + lane * 8 + 4];
        float bestv = -3.4e38f; bestc = 1 << 30;

        auto score = [&](int c) {
            float inv = inv_norm[c];
            const float4 ea = *(const float4*)&embed[(size_t)c * KDIM + lane * 8];
            const float4 eb = *(const float4*)&embed[(size_t)c * KDIM + lane * 8 + 4];
            float s = 0.f;
            s = fmaf(xa.x, ea.x * inv, s); s = fmaf(xa.y, ea.y * inv, s);
            s = fmaf(xa.z, ea.z * inv, s); s = fmaf(xa.w, ea.w * inv, s);
            s = fmaf(xb.x, eb.x * inv, s); s = fmaf(xb.y, eb.y * inv, s);
            s = fmaf(xb.z, eb.z * inv, s); s = fmaf(xb.w, eb.w * inv, s);
#pragma unroll
            for (int off = 32; off >= 1; off >>= 1) s += __shfl_xor(s, off, 64);
            if (s > bestv || (s == bestv && c < bestc)) { bestv = s; bestc = c; }
        };

        const int h0 = (gap > TAU) ? lead : 0;
        const int h1 = (gap > TAU) ? lead : 1;
        for (int h = h0; h <= h1; ++h) {
            const unsigned ch = h ? c1 : c0;
            if (ch <= CAPH) {
                for (unsigned i = 0; i < ch; ++i)
                    score((int)cand_g[(size_t)r * 32 + h * 16 + i]);
            } else {
                // candidate list overflowed (P ~ 1e-9/half-row): exact scan of the half
                for (int c = h * NHALF; c < h * NHALF + NHALF; ++c) score(c);
            }
        }
    }

    if (lane == 0) out_i[r] = (float)bestc;
    const float4 qa = *(const float4*)&embed[(size_t)bestc * KDIM + lane * 8];
    const float4 qb = *(const float4*)&embed[(size_t)bestc * KDIM + lane * 8 + 4];
    *(float4*)&out_q[(size_t)r * KDIM + lane * 8]     = qa;
    *(float4*)&out_q[(size_t)r * KDIM + lane * 8 + 4] = qb;
}

// ================= fallback (round-2 kernel, known correct) =================
#define FBM   64
#define FBN   256
#define FBK   16

__global__ __launch_bounds__(256, 1)
void vq_norm_kernel(const float* __restrict__ embed, float* __restrict__ inv_norm) {
    const int row  = blockIdx.x * 4 + (threadIdx.x >> 6);
    const int lane = threadIdx.x & 63;
    const float* e = embed + (size_t)row * KDIM;
    float ss = 0.f;
#pragma unroll
    for (int p = 0; p < 8; ++p) { float v = e[lane + 64 * p]; ss = fmaf(v, v, ss); }
#pragma unroll
    for (int off = 32; off >= 1; off >>= 1) ss += __shfl_xor(ss, off, 64);
    if (lane == 0) inv_norm[row] = 1.0f / fmaxf(sqrtf(ss), 1e-12f);
}

__global__ __launch_bounds__(256, 2)
void vq_main_kernel(const float* __restrict__ x, const float* __restrict__ embed,
                    const float* __restrict__ inv_norm,
                    float* __restrict__ out_q, float* __restrict__ out_i) {
    __shared__ float As[FBK][FBM + 4];
    __shared__ float Bs[FBK][FBN + 4];
    __shared__ float best_val[FBM];
    __shared__ int   best_idx[FBM];
    const int tid = threadIdx.x;
    const int m0  = blockIdx.x * FBM;
    const int ty  = tid >> 5, tx = tid & 31;
    if (tid < FBM) { best_val[tid] = -3.0e38f; best_idx[tid] = 0; }
    const int am = tid >> 2, k4 = (tid & 3) << 2, bc = tid >> 2;
    float acc[8][8];
    for (int n0 = 0; n0 < CDIM; n0 += FBN) {
        float bs0 = inv_norm[n0+bc], bs1 = inv_norm[n0+bc+64], bs2 = inv_norm[n0+bc+128], bs3 = inv_norm[n0+bc+192];
#pragma unroll
        for (int i = 0; i < 8; ++i)
#pragma unroll
            for (int j = 0; j < 8; ++j) acc[i][j] = 0.f;
        float4 aReg = *(const float4*)&x[(size_t)(m0+am)*KDIM + k4];
        float4 b0 = *(const float4*)&embed[(size_t)(n0+bc)*KDIM + k4];
        float4 b1 = *(const float4*)&embed[(size_t)(n0+bc+64)*KDIM + k4];
        float4 b2 = *(const float4*)&embed[(size_t)(n0+bc+128)*KDIM + k4];
        float4 b3 = *(const float4*)&embed[(size_t)(n0+bc+192)*KDIM + k4];
        for (int kt = 0; kt < KDIM; kt += FBK) {
            __syncthreads();
            As[k4+0][am]=aReg.x; As[k4+1][am]=aReg.y; As[k4+2][am]=aReg.z; As[k4+3][am]=aReg.w;
            Bs[k4+0][bc]=b0.x*bs0; Bs[k4+1][bc]=b0.y*bs0; Bs[k4+2][bc]=b0.z*bs0; Bs[k4+3][bc]=b0.w*bs0;
            Bs[k4+0][bc+64]=b1.x*bs1; Bs[k4+1][bc+64]=b1.y*bs1; Bs[k4+2][bc+64]=b1.z*bs1; Bs[k4+3][bc+64]=b1.w*bs1;
            Bs[k4+0][bc+128]=b2.x*bs2; Bs[k4+1][bc+128]=b2.y*bs2; Bs[k4+2][bc+128]=b2.z*bs2; Bs[k4+3][bc+128]=b2.w*bs2;
            Bs[k4+0][bc+192]=b3.x*bs3; Bs[k4+1][bc+192]=b3.y*bs3; Bs[k4+2][bc+192]=b3.z*bs3; Bs[k4+3][bc+192]=b3.w*bs3;
            __syncthreads();
            if (kt + FBK < KDIM) {
                int kn = kt + FBK + k4;
                aReg = *(const float4*)&x[(size_t)(m0+am)*KDIM + kn];
                b0 = *(const float4*)&embed[(size_t)(n0+bc)*KDIM + kn];
                b1 = *(const float4*)&embed[(size_t)(n0+bc+64)*KDIM + kn];
                b2 = *(const float4*)&embed[(size_t)(n0+bc+128)*KDIM + kn];
                b3 = *(const float4*)&embed[(size_t)(n0+bc+192)*KDIM + kn];
            }
#pragma unroll 4
            for (int k = 0; k < FBK; ++k) {
                float a[8], b[8];
                *(float4*)&a[0] = *(const float4*)&As[k][ty*8];
                *(float4*)&a[4] = *(const float4*)&As[k][ty*8+4];
                *(float4*)&b[0] = *(const float4*)&Bs[k][tx*4];
                *(float4*)&b[4] = *(const float4*)&Bs[k][128+tx*4];
#pragma unroll
                for (int i = 0; i < 8; ++i)
#pragma unroll
                    for (int j = 0; j < 8; ++j) acc[i][j] = fmaf(a[i], b[j], acc[i][j]);
            }
        }
#pragma unroll
        for (int i = 0; i < 8; ++i) {
            float v = acc[i][0]; int jj = 0;
#pragma unroll
            for (int j = 1; j < 8; ++j) if (acc[i][j] > v) { v = acc[i][j]; jj = j; }
            int col = n0 + ((jj < 4) ? (tx*4+jj) : (128 + tx*4 + (jj-4)));
#pragma unroll
            for (int off = 16; off >= 1; off >>= 1) {
                float ov = __shfl_xor(v, off, 64);
                int   oc = __shfl_xor(col, off, 64);
                if (ov > v || (ov == v && oc < col)) { v = ov; col = oc; }
            }
            if (tx == 0) {
                int r = ty*8+i;
                if (v > best_val[r] || (v == best_val[r] && col < best_idx[r])) { best_val[r]=v; best_idx[r]=col; }
            }
        }
    }
    __syncthreads();
    if (tid < FBM) out_i[m0 + tid] = (float)best_idx[tid];
#pragma unroll 1
    for (int rp = 0; rp < FBM; rp += 2) {
        int r = rp + (tid >> 7), slot = tid & 127, src = best_idx[r];
        const float4 v = *(const float4*)&embed[(size_t)src*KDIM + slot*4];
        *(float4*)&out_q[(size_t)(m0+r)*KDIM + slot*4] = v;
    }
}

extern "C" void kernel_launch(void* const* d_in, const int* in_sizes, int n_in,
                              void* d_out, int out_size, void* d_ws, size_t ws_size,
                              hipStream_t stream) {
    const float* x     = (const float*)d_in[0];
    const float* embed = (const float*)d_in[1];
    float* out_q = (float*)d_out;
    float* out_i = (float*)d_out + (size_t)MTOT * KDIM;
    char*  ws    = (char*)d_ws;

    if (ws_size >= (size_t)WS_NEEDED) {
        unsigned short* xh  = (unsigned short*)(ws + XH_OFF);
        unsigned short* eh  = (unsigned short*)(ws + EH_OFF);
        float*          inv = (float*)(ws + INV_OFF);
        unsigned*       cnt = (unsigned*)(ws + CNT_OFF);
        float*          bv  = (float*)(ws + BV_OFF);
        unsigned short* cnd = (unsigned short*)(ws + CAND_OFF);

        vq_norm_eh_kernel<<<CDIM / 4, 256, 0, stream>>>(embed, inv, eh);
        vq_convx_kernel<<<(MTOT * KDIM / 8) / 256, 256, 0, stream>>>(x, xh);
        vq_phase1_kernel<<<(MTOT / BM) * 2, 512, 0, stream>>>(xh, eh, cnt, bv, cnd);
        vq_phase2_kernel<<<MTOT / 4, 256, 0, stream>>>(x, embed, inv, cnt, bv, cnd, out_q, out_i);
    } else {
        float* inv = (float*)ws;   // 8 KB
        vq_norm_kernel<<<CDIM / 4, 256, 0, stream>>>(embed, inv);
        vq_main_kernel<<<MTOT / FBM, 256, 0, stream>>>(x, embed, inv, out_q, out_i);
    }
}

// Round 12
// 138.469 us; speedup vs baseline: 52.6579x; 1.5407x over previous
//
#include <hip/hip_runtime.h>

#define MTOT 32768   // B*N
#define KDIM 512     // D
#define CDIM 2048    // C
#define NHALF 1024   // codes per block-half
#define CAPH 16      // candidate slots per row per half
#define TAU  0.032f  // candidate window (~14 sigma of bf16 rounding noise)
#define BM   128     // rows per block
#define NS   64      // K-steps: 4 n-tiles x 16 steps of K=32

// ---- workspace layout (bytes) ----
#define XH_OFF   0u
#define XH_SZ    (MTOT * KDIM * 2u)          // 32 MB bf16 x
#define EH_OFF   (XH_OFF + XH_SZ)
#define EH_SZ    (CDIM * KDIM * 2u)          // 2 MB bf16 normalized codebook
#define INV_OFF  (EH_OFF + EH_SZ)
#define INV_SZ   (CDIM * 4u)
#define CNT_OFF  (INV_OFF + INV_SZ)
#define CNT_SZ   (2u * MTOT * 4u)
#define BV_OFF   (CNT_OFF + CNT_SZ)
#define BV_SZ    (2u * MTOT * 4u)
#define CAND_OFF (BV_OFF + BV_SZ)
#define CAND_SZ  (MTOT * 32u * 2u)           // u16 codes, [row][2*CAPH]
#define WS_NEEDED (CAND_OFF + CAND_SZ)

typedef short  short8 __attribute__((ext_vector_type(8)));
typedef float  f32x4  __attribute__((ext_vector_type(4)));

__device__ inline unsigned short f2bf(float f) {
    unsigned u = __float_as_uint(f);
    return (unsigned short)((u + 0x7FFFu + ((u >> 16) & 1u)) >> 16);  // RTNE
}
__device__ inline unsigned fkey(float f) {          // order-preserving f32->u32
    unsigned u = __float_as_uint(f);
    return (u & 0x80000000u) ? ~u : (u | 0x80000000u);
}
__device__ inline float fkey_inv(unsigned k) {
    unsigned u = (k & 0x80000000u) ? (k ^ 0x80000000u) : ~k;
    return __uint_as_float(u);
}
__device__ __forceinline__ void async16(void* lds, const void* g) {
    __builtin_amdgcn_global_load_lds(
        (const __attribute__((address_space(1))) unsigned int*)g,
        (__attribute__((address_space(3))) unsigned int*)lds, 16, 0, 0);
}

// ---------- fused prep: codebook norms + bf16 codebook + x -> bf16 ----------
// blocks [0, 512): norm_eh over 4 codebook rows each.
// blocks [512, 512+8192): convx over 2048 x-elements each.
__global__ __launch_bounds__(256, 1)
void vq_prep_kernel(const float* __restrict__ embed, const float* __restrict__ x,
                    float* __restrict__ inv_norm, unsigned short* __restrict__ eh,
                    unsigned short* __restrict__ xh) {
    if (blockIdx.x < 512) {
        const int row  = blockIdx.x * 4 + (threadIdx.x >> 6);
        const int lane = threadIdx.x & 63;
        const float4 v0 = *(const float4*)&embed[(size_t)row * KDIM + lane * 8];
        const float4 v1 = *(const float4*)&embed[(size_t)row * KDIM + lane * 8 + 4];
        float ss = v0.x*v0.x + v0.y*v0.y + v0.z*v0.z + v0.w*v0.w
                 + v1.x*v1.x + v1.y*v1.y + v1.z*v1.z + v1.w*v1.w;
#pragma unroll
        for (int off = 32; off >= 1; off >>= 1) ss += __shfl_xor(ss, off, 64);
        float inv = 1.0f / fmaxf(sqrtf(ss), 1e-12f);
        if (lane == 0) inv_norm[row] = inv;
        short8 o;
        o[0] = (short)f2bf(v0.x * inv); o[1] = (short)f2bf(v0.y * inv);
        o[2] = (short)f2bf(v0.z * inv); o[3] = (short)f2bf(v0.w * inv);
        o[4] = (short)f2bf(v1.x * inv); o[5] = (short)f2bf(v1.y * inv);
        o[6] = (short)f2bf(v1.z * inv); o[7] = (short)f2bf(v1.w * inv);
        *(short8*)&eh[(size_t)row * KDIM + lane * 8] = o;
    } else {
        const size_t base = ((size_t)(blockIdx.x - 512) * 256 + threadIdx.x) * 8;
        const float4 a = *(const float4*)&x[base];
        const float4 b = *(const float4*)&x[base + 4];
        short8 o;
        o[0] = (short)f2bf(a.x); o[1] = (short)f2bf(a.y);
        o[2] = (short)f2bf(a.z); o[3] = (short)f2bf(a.w);
        o[4] = (short)f2bf(b.x); o[5] = (short)f2bf(b.y);
        o[6] = (short)f2bf(b.z); o[7] = (short)f2bf(b.w);
        *(short8*)&xh[base] = o;
    }
}

// ---------------- phase 1: bf16 MFMA GEMM + max + candidate window ----------------
// R9-verified structure (96.4 us): grid 512 -> 2 blocks/CU (53 KB LDS each);
// 8 waves 2(m)x4(n); wave tile 64x64 = 4x4 fragments of 16x16; BK=32;
// A+B in triple-buffered swizzled LDS via global_load_lds; counted vmcnt(3);
// one barrier per K-step; row-pair layout -> ds_read = base VGPR + immediate.
// NEW (perf-only): XCD-chunked bijective blockIdx swizzle (512 = 8 XCD x 64):
// pairs the two halves of a row-block (shared 128KB xh panel) on one XCD L2.
__global__ __launch_bounds__(512, 4)
void vq_phase1_kernel(const unsigned short* __restrict__ xh,
                      const unsigned short* __restrict__ eh,
                      unsigned* __restrict__ cnt_g, float* __restrict__ bv_g,
                      unsigned short* __restrict__ cand_g) {
    __shared__ __align__(16) char abuf[3 * 8192];    // 24 KB: 3 x (128 rows x 32k x 2B)
    __shared__ __align__(16) char bbuf[3 * 16384];   // 48 KB: 3 x (256 codes x 32k x 2B)
    __shared__ unsigned runmax[BM];
    __shared__ unsigned cnt[BM];
    __shared__ unsigned short cand[BM][CAPH];

    const int tid  = threadIdx.x;
    const int lane = tid & 63;
    const int wid  = tid >> 6;
    const int wr   = wid >> 2;          // 0..1 -> 64 rows
    const int wc   = wid & 3;           // 0..3 -> 64 codes
    const int bid0 = blockIdx.x;
    const int vbid = (bid0 & 7) * 64 + (bid0 >> 3);   // bijective XCD chunking
    const int m0   = (vbid >> 1) * BM;
    const int half = vbid & 1;
    const int n0b  = half * NHALF;

    const int laneRow = lane & 15;
    const int laneK8  = lane >> 4;              // 0..3 -> k-chunk of 8
    const int rr      = laneRow >> 1;           // 0..7
    const int slot8s  = (((laneRow & 1) << 2) + laneK8) ^ rr;

    if (tid < BM) { runmax[tid] = 0u; cnt[tid] = 0u; }

    // ---- per-lane ds_read bases (byte offsets; all variation is immediate) ----
    const char* aRd = abuf + (wr * 4096 + rr * 128 + slot8s * 16);
    const char* bRd = bbuf + (wc * 4096 + rr * 128 + slot8s * 16);

    // ---- per-lane staging source pointers (layout-inverse swizzle, rule 21) ----
    const unsigned short* aSrc;
    {
        int rp  = tid >> 3;                     // 0..63
        int s8  = (tid & 7) ^ (rp & 7);
        int row = rp * 2 + (s8 >> 2);           // 0..127
        int k8  = s8 & 3;
        aSrc = xh + (size_t)(m0 + row) * KDIM + k8 * 8;
    }
    const unsigned short* bSrc[2];
#pragma unroll
    for (int l = 0; l < 2; ++l) {
        int slot = l * 512 + tid;
        int rp   = slot >> 3;                   // 0..127
        int s8   = (slot & 7) ^ (rp & 7);
        int row  = rp * 2 + (s8 >> 2);          // 0..255
        int k8   = s8 & 3;
        bSrc[l] = eh + (size_t)(n0b + row) * KDIM + k8 * 8;
    }
    const int ldsW  = wid * 1024;               // wave-uniform dest base
    const int ldsW1 = 8192 + wid * 1024;        // B second half

    f32x4 acc[4][4];

    // stage K-step S into buffer S%3 (3 loads/thread: 1 A + 2 B)
#define STAGE(S) {                                                        \
        const int _ao = ((S) & 15) * 32;                                  \
        const int _bo = ((S) >> 4) * 131072 + _ao;                        \
        async16(abuf + ((S) % 3) * 8192  + ldsW,  aSrc    + _ao);         \
        async16(bbuf + ((S) % 3) * 16384 + ldsW,  bSrc[0] + _bo);         \
        async16(bbuf + ((S) % 3) * 16384 + ldsW1, bSrc[1] + _bo);         \
    }

#define STEP(S, BUF) {                                                    \
        if ((S) == NS - 1) { asm volatile("s_waitcnt vmcnt(0)" ::: "memory"); } \
        else               { asm volatile("s_waitcnt vmcnt(3)" ::: "memory"); } \
        __builtin_amdgcn_sched_barrier(0);                                \
        __builtin_amdgcn_s_barrier();                                     \
        __builtin_amdgcn_sched_barrier(0);                                \
        if ((S) + 2 < NS) STAGE((S) + 2);                                 \
        if (((S) & 15) == 0) {                                            \
            _Pragma("unroll")                                             \
            for (int i = 0; i < 4; ++i)                                   \
                _Pragma("unroll")                                         \
                for (int j = 0; j < 4; ++j) acc[i][j] = (f32x4)0.0f;      \
        }                                                                 \
        short8 af[4], bf[4];                                              \
        _Pragma("unroll")                                                 \
        for (int ai = 0; ai < 4; ++ai)                                    \
            af[ai] = *(const short8*)(aRd + ((BUF) * 8192 + ai * 1024));  \
        _Pragma("unroll")                                                 \
        for (int aj = 0; aj < 4; ++aj)                                    \
            bf[aj] = *(const short8*)(bRd + ((BUF) * 16384 + aj * 1024)); \
        __builtin_amdgcn_s_setprio(1);                                    \
        _Pragma("unroll")                                                 \
        for (int ai = 0; ai < 4; ++ai)                                    \
            _Pragma("unroll")                                             \
            for (int aj = 0; aj < 4; ++aj)                                \
                acc[ai][aj] = __builtin_amdgcn_mfma_f32_16x16x32_bf16(    \
                    af[ai], bf[aj], acc[ai][aj], 0, 0, 0);                \
        __builtin_amdgcn_s_setprio(0);                                    \
        if (((S) & 15) == 15) {                                           \
            const int _n0 = n0b + ((S) >> 4) * 256;                       \
            _Pragma("unroll")                                             \
            for (int ai = 0; ai < 4; ++ai) {                              \
                _Pragma("unroll")                                         \
                for (int r = 0; r < 4; ++r) {                             \
                    float v = fmaxf(fmaxf(acc[ai][0][r], acc[ai][1][r]),  \
                                    fmaxf(acc[ai][2][r], acc[ai][3][r])); \
                    _Pragma("unroll")                                     \
                    for (int off = 8; off >= 1; off >>= 1)                \
                        v = fmaxf(v, __shfl_xor(v, off, 64));             \
                    if (laneRow == 0)                                     \
                        atomicMax(&runmax[wr * 64 + ai * 16 + laneK8 * 4 + r], fkey(v)); \
                }                                                         \
            }                                                             \
            asm volatile("s_waitcnt lgkmcnt(0)" ::: "memory");            \
            __builtin_amdgcn_sched_barrier(0);                            \
            __builtin_amdgcn_s_barrier();                                 \
            __builtin_amdgcn_sched_barrier(0);                            \
            _Pragma("unroll")                                             \
            for (int ai = 0; ai < 4; ++ai) {                              \
                const int _rb = wr * 64 + ai * 16 + laneK8 * 4;           \
                _Pragma("unroll")                                         \
                for (int r = 0; r < 4; ++r) {                             \
                    float th = fkey_inv(runmax[_rb + r]) - TAU;           \
                    _Pragma("unroll")                                     \
                    for (int aj = 0; aj < 4; ++aj) {                      \
                        if (acc[ai][aj][r] >= th) {                       \
                            unsigned idx = atomicAdd(&cnt[_rb + r], 1u);  \
                            if (idx < CAPH)                               \
                                cand[_rb + r][idx] = (unsigned short)     \
                                    (_n0 + wc * 64 + aj * 16 + laneRow);  \
                        }                                                 \
                    }                                                     \
                }                                                         \
            }                                                             \
        }                                                                 \
    }

    STAGE(0);
    STAGE(1);
#pragma unroll 1
    for (int sb = 0; sb < NS; sb += 3) {
        STEP(sb + 0, 0);
        if (sb + 1 < NS) STEP(sb + 1, 1);
        if (sb + 2 < NS) STEP(sb + 2, 2);
    }
#undef STEP
#undef STAGE

    __syncthreads();
    if (tid < BM) {
        cnt_g[(size_t)half * MTOT + m0 + tid] = cnt[tid];              // RAW count
        bv_g [(size_t)half * MTOT + m0 + tid] = fkey_inv(runmax[tid]);
    }
#pragma unroll
    for (int l = 0; l < 4; ++l) {
        int i = tid + l * 512;           // 0..2047 = 128 rows x 16 slots
        int row = i >> 4, sl = i & 15;
        cand_g[(size_t)(m0 + row) * 32 + half * 16 + sl] = cand[row][sl];
    }
}

// ---------------- phase 2: cross-half resolve + rare fp32 rescore + gather ----------
__global__ __launch_bounds__(256, 2)
void vq_phase2_kernel(const float* __restrict__ x, const float* __restrict__ embed,
                      const float* __restrict__ inv_norm,
                      const unsigned* __restrict__ cnt_g, const float* __restrict__ bv_g,
                      const unsigned short* __restrict__ cand_g,
                      float* __restrict__ out_q, float* __restrict__ out_i) {
    const int r    = blockIdx.x * 4 + (threadIdx.x >> 6);
    const int lane = threadIdx.x & 63;

    const unsigned c0 = cnt_g[r], c1 = cnt_g[(size_t)MTOT + r];
    const float bv0 = bv_g[r], bv1 = bv_g[(size_t)MTOT + r];
    const int   lead = (bv1 > bv0) ? 1 : 0;
    const float gap  = fabsf(bv0 - bv1);
    const unsigned cl = lead ? c1 : c0;

    int bestc;
    if (gap > TAU && cl == 1) {
        bestc = (int)cand_g[(size_t)r * 32 + lead * 16];   // unique near-max candidate
    } else {
        const float4 xa = *(const float4*)&x[(size_t)r * KDIM + lane * 8];
        const float4 xb = *(const float4*)&x[(size_t)r * KDIM + lane * 8 + 4];
        float bestv = -3.4e38f; bestc = 1 << 30;

        auto score = [&](int c) {
            float inv = inv_norm[c];
            const float4 ea = *(const float4*)&embed[(size_t)c * KDIM + lane * 8];
            const float4 eb = *(const float4*)&embed[(size_t)c * KDIM + lane * 8 + 4];
            float s = 0.f;
            s = fmaf(xa.x, ea.x * inv, s); s = fmaf(xa.y, ea.y * inv, s);
            s = fmaf(xa.z, ea.z * inv, s); s = fmaf(xa.w, ea.w * inv, s);
            s = fmaf(xb.x, eb.x * inv, s); s = fmaf(xb.y, eb.y * inv, s);
            s = fmaf(xb.z, eb.z * inv, s); s = fmaf(xb.w, eb.w * inv, s);
#pragma unroll
            for (int off = 32; off >= 1; off >>= 1) s += __shfl_xor(s, off, 64);
            if (s > bestv || (s == bestv && c < bestc)) { bestv = s; bestc = c; }
        };

        const int h0 = (gap > TAU) ? lead : 0;
        const int h1 = (gap > TAU) ? lead : 1;
        for (int h = h0; h <= h1; ++h) {
            const unsigned ch = h ? c1 : c0;
            if (ch <= CAPH) {
                for (unsigned i = 0; i < ch; ++i)
                    score((int)cand_g[(size_t)r * 32 + h * 16 + i]);
            } else {
                // candidate list overflowed (P ~ 1e-9/half-row): exact scan of the half
                for (int c = h * NHALF; c < h * NHALF + NHALF; ++c) score(c);
            }
        }
    }

    if (lane == 0) out_i[r] = (float)bestc;
    const float4 qa = *(const float4*)&embed[(size_t)bestc * KDIM + lane * 8];
    const float4 qb = *(const float4*)&embed[(size_t)bestc * KDIM + lane * 8 + 4];
    *(float4*)&out_q[(size_t)r * KDIM + lane * 8]     = qa;
    *(float4*)&out_q[(size_t)r * KDIM + lane * 8 + 4] = qb;
}

// ================= fallback (round-2 kernel, known correct) =================
#define FBM   64
#define FBN   256
#define FBK   16

__global__ __launch_bounds__(256, 1)
void vq_norm_kernel(const float* __restrict__ embed, float* __restrict__ inv_norm) {
    const int row  = blockIdx.x * 4 + (threadIdx.x >> 6);
    const int lane = threadIdx.x & 63;
    const float* e = embed + (size_t)row * KDIM;
    float ss = 0.f;
#pragma unroll
    for (int p = 0; p < 8; ++p) { float v = e[lane + 64 * p]; ss = fmaf(v, v, ss); }
#pragma unroll
    for (int off = 32; off >= 1; off >>= 1) ss += __shfl_xor(ss, off, 64);
    if (lane == 0) inv_norm[row] = 1.0f / fmaxf(sqrtf(ss), 1e-12f);
}

__global__ __launch_bounds__(256, 2)
void vq_main_kernel(const float* __restrict__ x, const float* __restrict__ embed,
                    const float* __restrict__ inv_norm,
                    float* __restrict__ out_q, float* __restrict__ out_i) {
    __shared__ float As[FBK][FBM + 4];
    __shared__ float Bs[FBK][FBN + 4];
    __shared__ float best_val[FBM];
    __shared__ int   best_idx[FBM];
    const int tid = threadIdx.x;
    const int m0  = blockIdx.x * FBM;
    const int ty  = tid >> 5, tx = tid & 31;
    if (tid < FBM) { best_val[tid] = -3.0e38f; best_idx[tid] = 0; }
    const int am = tid >> 2, k4 = (tid & 3) << 2, bc = tid >> 2;
    float acc[8][8];
    for (int n0 = 0; n0 < CDIM; n0 += FBN) {
        float bs0 = inv_norm[n0+bc], bs1 = inv_norm[n0+bc+64], bs2 = inv_norm[n0+bc+128], bs3 = inv_norm[n0+bc+192];
#pragma unroll
        for (int i = 0; i < 8; ++i)
#pragma unroll
            for (int j = 0; j < 8; ++j) acc[i][j] = 0.f;
        float4 aReg = *(const float4*)&x[(size_t)(m0+am)*KDIM + k4];
        float4 b0 = *(const float4*)&embed[(size_t)(n0+bc)*KDIM + k4];
        float4 b1 = *(const float4*)&embed[(size_t)(n0+bc+64)*KDIM + k4];
        float4 b2 = *(const float4*)&embed[(size_t)(n0+bc+128)*KDIM + k4];
        float4 b3 = *(const float4*)&embed[(size_t)(n0+bc+192)*KDIM + k4];
        for (int kt = 0; kt < KDIM; kt += FBK) {
            __syncthreads();
            As[k4+0][am]=aReg.x; As[k4+1][am]=aReg.y; As[k4+2][am]=aReg.z; As[k4+3][am]=aReg.w;
            Bs[k4+0][bc]=b0.x*bs0; Bs[k4+1][bc]=b0.y*bs0; Bs[k4+2][bc]=b0.z*bs0; Bs[k4+3][bc]=b0.w*bs0;
            Bs[k4+0][bc+64]=b1.x*bs1; Bs[k4+1][bc+64]=b1.y*bs1; Bs[k4+2][bc+64]=b1.z*bs1; Bs[k4+3][bc+64]=b1.w*bs1;
            Bs[k4+0][bc+128]=b2.x*bs2; Bs[k4+1][bc+128]=b2.y*bs2; Bs[k4+2][bc+128]=b2.z*bs2; Bs[k4+3][bc+128]=b2.w*bs2;
            Bs[k4+0][bc+192]=b3.x*bs3; Bs[k4+1][bc+192]=b3.y*bs3; Bs[k4+2][bc+192]=b3.z*bs3; Bs[k4+3][bc+192]=b3.w*bs3;
            __syncthreads();
            if (kt + FBK < KDIM) {
                int kn = kt + FBK + k4;
                aReg = *(const float4*)&x[(size_t)(m0+am)*KDIM + kn];
                b0 = *(const float4*)&embed[(size_t)(n0+bc)*KDIM + kn];
                b1 = *(const float4*)&embed[(size_t)(n0+bc+64)*KDIM + kn];
                b2 = *(const float4*)&embed[(size_t)(n0+bc+128)*KDIM + kn];
                b3 = *(const float4*)&embed[(size_t)(n0+bc+192)*KDIM + kn];
            }
#pragma unroll 4
            for (int k = 0; k < FBK; ++k) {
                float a[8], b[8];
                *(float4*)&a[0] = *(const float4*)&As[k][ty*8];
                *(float4*)&a[4] = *(const float4*)&As[k][ty*8+4];
                *(float4*)&b[0] = *(const float4*)&Bs[k][tx*4];
                *(float4*)&b[4] = *(const float4*)&Bs[k][128+tx*4];
#pragma unroll
                for (int i = 0; i < 8; ++i)
#pragma unroll
                    for (int j = 0; j < 8; ++j) acc[i][j] = fmaf(a[i], b[j], acc[i][j]);
            }
        }
#pragma unroll
        for (int i = 0; i < 8; ++i) {
            float v = acc[i][0]; int jj = 0;
#pragma unroll
            for (int j = 1; j < 8; ++j) if (acc[i][j] > v) { v = acc[i][j]; jj = j; }
            int col = n0 + ((jj < 4) ? (tx*4+jj) : (128 + tx*4 + (jj-4)));
#pragma unroll
            for (int off = 16; off >= 1; off >>= 1) {
                float ov = __shfl_xor(v, off, 64);
                int   oc = __shfl_xor(col, off, 64);
                if (ov > v || (ov == v && oc < col)) { v = ov; col = oc; }
            }
            if (tx == 0) {
                int r = ty*8+i;
                if (v > best_val[r] || (v == best_val[r] && col < best_idx[r])) { best_val[r]=v; best_idx[r]=col; }
            }
        }
    }
    __syncthreads();
    if (tid < FBM) out_i[m0 + tid] = (float)best_idx[tid];
#pragma unroll 1
    for (int rp = 0; rp < FBM; rp += 2) {
        int r = rp + (tid >> 7), slot = tid & 127, src = best_idx[r];
        const float4 v = *(const float4*)&embed[(size_t)src*KDIM + slot*4];
        *(float4*)&out_q[(size_t)(m0+r)*KDIM + slot*4] = v;
    }
}

extern "C" void kernel_launch(void* const* d_in, const int* in_sizes, int n_in,
                              void* d_out, int out_size, void* d_ws, size_t ws_size,
                              hipStream_t stream) {
    const float* x     = (const float*)d_in[0];
    const float* embed = (const float*)d_in[1];
    float* out_q = (float*)d_out;
    float* out_i = (float*)d_out + (size_t)MTOT * KDIM;
    char*  ws    = (char*)d_ws;

    if (ws_size >= (size_t)WS_NEEDED) {
        unsigned short* xh  = (unsigned short*)(ws + XH_OFF);
        unsigned short* eh  = (unsigned short*)(ws + EH_OFF);
        float*          inv = (float*)(ws + INV_OFF);
        unsigned*       cnt = (unsigned*)(ws + CNT_OFF);
        float*          bv  = (float*)(ws + BV_OFF);
        unsigned short* cnd = (unsigned short*)(ws + CAND_OFF);

        vq_prep_kernel<<<512 + (MTOT * KDIM / 8) / 256, 256, 0, stream>>>(embed, x, inv, eh, xh);
        vq_phase1_kernel<<<(MTOT / BM) * 2, 512, 0, stream>>>(xh, eh, cnt, bv, cnd);
        vq_phase2_kernel<<<MTOT / 4, 256, 0, stream>>>(x, embed, inv, cnt, bv, cnd, out_q, out_i);
    } else {
        float* inv = (float*)ws;   // 8 KB
        vq_norm_kernel<<<CDIM / 4, 256, 0, stream>>>(embed, inv);
        vq_main_kernel<<<MTOT / FBM, 256, 0, stream>>>(x, embed, inv, out_q, out_i);
    }
}